// Round 2
// baseline (32960.062 us; speedup 1.0000x reference)
//
#include <hip/hip_runtime.h>
#include <hip/hip_fp16.h>

#define LOG2E 1.44269504088896340736f
#define BB 256
#define TT 128
#define SS 128
#define UU 256

// ---------------- parameter precompute ----------------
// sigmoid(sigma*(v-mu)) = 1/(1+2^(a*v+b)),  a=-sigma*log2e, b=sigma*mu*log2e
// w-signed = softplus(w)*erev ; |w| recovered via fabs (free operand modifier)
// recurrent: rab[i*UU+j] = half2(a,b); rwp[(i/2)*UU+j] = half2(w_i, w_{i+1})
// sensory:   sab[i*UU+j] = half2(a,b); swp[(i/2)*UU+j] = half2(w_i, w_{i+1})
// per-unit:  cmt = softplus(cm)*6 ; gnum = gl*vleak ; cden = cmt+gl+1e-8
__global__ __launch_bounds__(256) void prep_kernel(
    const float* __restrict__ sensory_w, const float* __restrict__ sensory_mu,
    const float* __restrict__ sensory_sigma, const float* __restrict__ sensory_erev,
    const float* __restrict__ w, const float* __restrict__ mu,
    const float* __restrict__ sigma, const float* __restrict__ erev,
    const float* __restrict__ gleak, const float* __restrict__ vleak,
    const float* __restrict__ cm,
    __half2* __restrict__ rab, __half2* __restrict__ rwp,
    __half2* __restrict__ sab, __half2* __restrict__ swp,
    float* __restrict__ cmt, float* __restrict__ gnum, float* __restrict__ cden)
{
    int e = blockIdx.x * 256 + threadIdx.x;      // e over UU*UU
    int i = e >> 8, j = e & (UU - 1);
    if (e < UU * UU) {
        float sg = sigma[e], m = mu[e];
        rab[e] = __floats2half2_rn(-sg * LOG2E, sg * m * LOG2E);
        if ((i & 1) == 0) {
            float w0 = log1pf(expf(w[e])) * erev[e];
            float w1 = log1pf(expf(w[e + UU])) * erev[e + UU];
            rwp[(i >> 1) * UU + j] = __floats2half2_rn(w0, w1);
        }
    }
    if (e < SS * UU) {
        float sg = sensory_sigma[e], m = sensory_mu[e];
        sab[e] = __floats2half2_rn(-sg * LOG2E, sg * m * LOG2E);
        if ((i & 1) == 0) {
            float w0 = log1pf(expf(sensory_w[e])) * sensory_erev[e];
            float w1 = log1pf(expf(sensory_w[e + UU])) * sensory_erev[e + UU];
            swp[(i >> 1) * UU + j] = __floats2half2_rn(w0, w1);
        }
    }
    if (e < UU) {
        float gl = log1pf(expf(gleak[e]));
        float c = log1pf(expf(cm[e])) * 6.0f;   // ODE_UNFOLDS=6, ts=1
        cmt[e] = c;
        gnum[e] = gl * vleak[e];
        cden[e] = c + gl + 1e-8f;
    }
}

// ---------------- main kernel: 1 block = 1 batch element, 16 waves ----------------
// wave (qi = w&3, qj = w>>2): owns recurrent tile i in [64qi,64qi+64) x j in [64qj,64qj+64)
// with params resident in 96 VGPRs/lane. v is lane-distributed: lane l of every
// qj-wave in row qi holds v[64qi+l] (redundant x4, removes second barrier).
__global__ __launch_bounds__(1024, 1) void ltc_kernel(
    const float* __restrict__ x,
    const float* __restrict__ input_w, const float* __restrict__ input_b,
    const float* __restrict__ halt_w, const float* __restrict__ halt_b,
    const float* __restrict__ out_w, const float* __restrict__ out_b,
    const __half2* __restrict__ rab_g, const __half2* __restrict__ rwp_g,
    const __half2* __restrict__ sab_g, const __half2* __restrict__ swp_g,
    const float* __restrict__ cmt_g, const float* __restrict__ gnum_g,
    const float* __restrict__ cden_g,
    float* __restrict__ readout, float* __restrict__ h_state, float* __restrict__ ponder_out)
{
    const int b   = blockIdx.x;
    const int tid = threadIdx.x;
    const int wv  = tid >> 6;
    const int l   = tid & 63;
    const int qi  = wv & 3;
    const int qj  = wv >> 2;
    const int j   = (qj << 6) + l;   // column this lane accumulates partials for
    const int uj  = (qi << 6) + l;   // unit whose state this lane owns

    __shared__ float np_sh[2][4][UU];
    __shared__ float dp_sh[2][4][UU];
    __shared__ __align__(16) float xin_sh[SS];
    __shared__ float red_sh[4];

    // ---- persistent register-resident recurrent params (96 VGPRs) ----
    __half2 rab[64];
    __half2 rwp[32];
#pragma unroll
    for (int k = 0; k < 64; ++k) rab[k] = rab_g[((qi << 6) + k) * UU + j];
#pragma unroll
    for (int k = 0; k < 32; ++k) rwp[k] = rwp_g[((qi << 5) + k) * UU + j];

    const float cmt_r = cmt_g[uj];
    const float bn0   = gnum_g[uj];
    const float bd0   = cden_g[uj];
    const float hw_r  = halt_w[uj];     // used by qj==0 waves
    const float hb    = halt_b[0];
    float iw = 0.f, ibv = 0.f;
    if (tid < SS) { iw = input_w[tid]; ibv = input_b[tid]; }

    float v = 0.0f;
    float pond = 0.0f;
    int pb = 0;

    for (int t = 0; t < TT; ++t) {
        // ---- input mapping ----
        if (tid < SS) xin_sh[tid] = fmaf(x[((size_t)b * TT + t) * SS + tid], iw, ibv);
        __syncthreads();

        // ---- sensory partials: i in [32qi, 32qi+32), once per t (L2 loads ok) ----
        {
            float rn = 0.f, rd = 0.f;
            const int i0 = qi << 5;
#pragma unroll 2
            for (int k = 0; k < 32; k += 4) {
                float4 xv = *(const float4*)&xin_sh[i0 + k];
                float xk[4] = {xv.x, xv.y, xv.z, xv.w};
                float2 wp2 = {0.f, 0.f};
#pragma unroll
                for (int m = 0; m < 4; ++m) {
                    int i = i0 + k + m;
                    float2 ab = __half22float2(sab_g[i * UU + j]);
                    float z = fmaf(ab.x, xk[m], ab.y);
                    float s = __builtin_amdgcn_rcpf(1.0f + __builtin_amdgcn_exp2f(z));
                    if ((m & 1) == 0) wp2 = __half22float2(swp_g[(i >> 1) * UU + j]);
                    float wf = (m & 1) ? wp2.y : wp2.x;
                    rn = fmaf(wf, s, rn);
                    rd = fmaf(fabsf(wf), s, rd);
                }
            }
            np_sh[pb][qi][j] = rn;
            dp_sh[pb][qi][j] = rd;
        }
        __syncthreads();
        const float basen = np_sh[pb][0][uj] + np_sh[pb][1][uj] + np_sh[pb][2][uj]
                          + np_sh[pb][3][uj] + bn0;
        const float based = dp_sh[pb][0][uj] + dp_sh[pb][1][uj] + dp_sh[pb][2][uj]
                          + dp_sh[pb][3][uj] + bd0;
        pb ^= 1;

        float accr = 0.0f;
        float halt_sum = 0.0f, rem = 0.0f, n_upd = 0.0f;

        // ---- ACT loop (uniform early exit) ----
#pragma unroll 1
        for (int n = 0; n < 10; ++n) {
#pragma unroll 1
            for (int u = 0; u < 6; ++u) {
                // partials over i-block via readlane-broadcast v, register params
                float rn = 0.f, rd = 0.f;
                float2 wp2 = {0.f, 0.f};
#pragma unroll
                for (int k = 0; k < 64; ++k) {
                    float vk = __int_as_float(__builtin_amdgcn_readlane(__float_as_int(v), k));
                    float2 ab = __half22float2(rab[k]);
                    float z = fmaf(ab.x, vk, ab.y);
                    float s = __builtin_amdgcn_rcpf(1.0f + __builtin_amdgcn_exp2f(z));
                    if ((k & 1) == 0) wp2 = __half22float2(rwp[k >> 1]);
                    float wf = (k & 1) ? wp2.y : wp2.x;
                    rn = fmaf(wf, s, rn);
                    rd = fmaf(fabsf(wf), s, rd);
                }
                np_sh[pb][qi][j] = rn;
                dp_sh[pb][qi][j] = rd;
                __syncthreads();
                // every wave redundantly updates v for its own i-block (no 2nd barrier)
                float tn = np_sh[pb][0][uj] + np_sh[pb][1][uj] + np_sh[pb][2][uj]
                         + np_sh[pb][3][uj] + basen;
                float td = dp_sh[pb][0][uj] + dp_sh[pb][1][uj] + dp_sh[pb][2][uj]
                         + dp_sh[pb][3][uj] + based;
                float r0 = __builtin_amdgcn_rcpf(td);
                r0 = r0 * fmaf(-td, r0, 2.0f);           // 1 Newton step
                v = fmaf(cmt_r, v, tn) * r0;
                pb ^= 1;
            }

            // halting p = sigmoid(v . halt_w + hb); waves qj==0 hold full v
            if (qj == 0) {
                float hp = v * hw_r;
                hp += __shfl_down(hp, 32, 64);
                hp += __shfl_down(hp, 16, 64);
                hp += __shfl_down(hp, 8, 64);
                hp += __shfl_down(hp, 4, 64);
                hp += __shfl_down(hp, 2, 64);
                hp += __shfl_down(hp, 1, 64);
                if (l == 0) red_sh[qi] = hp;
            }
            __syncthreads();
            // all waves redundantly (identical arithmetic -> identical decision)
            float dot = red_sh[0] + red_sh[1] + red_sh[2] + red_sh[3] + hb;
            float pr = __builtin_amdgcn_rcpf(1.0f + __builtin_amdgcn_exp2f(-dot * LOG2E));
            float new_sum = halt_sum + pr;
            bool halting = (n == 9) || (new_sum >= 0.99f);
            float r = 1.0f - halt_sum;
            float wgt = halting ? r : pr;
            accr = fmaf(wgt, v, accr);
            if (halting) rem += r;
            halt_sum = new_sum;
            n_upd += 1.0f;
            if (halting) break;
        }

        // ---- epilogue: new_state = accr ----
        if (qj == 0)
            readout[((size_t)b * TT + t) * UU + uj] = fmaf(accr, out_w[uj], out_b[uj]);
        v = accr;
        pond += n_upd + rem;
    }

    if (qj == 0) h_state[(size_t)b * UU + uj] = v;
    if (tid == 0) atomicAdd(ponder_out, pond * (1.0f / BB));
}

// ---------------- launch ----------------
extern "C" void kernel_launch(void* const* d_in, const int* in_sizes, int n_in,
                              void* d_out, int out_size, void* d_ws, size_t ws_size,
                              hipStream_t stream)
{
    const float* x             = (const float*)d_in[0];
    const float* input_w       = (const float*)d_in[1];
    const float* input_b       = (const float*)d_in[2];
    const float* sensory_w     = (const float*)d_in[3];
    const float* sensory_mu    = (const float*)d_in[4];
    const float* sensory_sigma = (const float*)d_in[5];
    const float* sensory_erev  = (const float*)d_in[6];
    const float* w             = (const float*)d_in[7];
    const float* mu            = (const float*)d_in[8];
    const float* sigma         = (const float*)d_in[9];
    const float* erev          = (const float*)d_in[10];
    const float* gleak         = (const float*)d_in[11];
    const float* vleak         = (const float*)d_in[12];
    const float* cm            = (const float*)d_in[13];
    const float* output_w      = (const float*)d_in[14];
    const float* output_b      = (const float*)d_in[15];
    const float* halt_w        = (const float*)d_in[16];
    const float* halt_b        = (const float*)d_in[17];

    float* readout = (float*)d_out;
    float* h_state = readout + (size_t)BB * TT * UU;
    float* ponder  = h_state + (size_t)BB * UU;

    char* wsb = (char*)d_ws;
    __half2* rab = (__half2*)wsb;  wsb += (size_t)UU * UU * sizeof(__half2);
    __half2* rwp = (__half2*)wsb;  wsb += (size_t)(UU / 2) * UU * sizeof(__half2);
    __half2* sab = (__half2*)wsb;  wsb += (size_t)SS * UU * sizeof(__half2);
    __half2* swp = (__half2*)wsb;  wsb += (size_t)(SS / 2) * UU * sizeof(__half2);
    float* cmt  = (float*)wsb;     wsb += (size_t)UU * 4;
    float* gnum = (float*)wsb;     wsb += (size_t)UU * 4;
    float* cden = (float*)wsb;     wsb += (size_t)UU * 4;

    hipMemsetAsync(ponder, 0, sizeof(float), stream);
    prep_kernel<<<(UU * UU) / 256, 256, 0, stream>>>(
        sensory_w, sensory_mu, sensory_sigma, sensory_erev,
        w, mu, sigma, erev, gleak, vleak, cm,
        rab, rwp, sab, swp, cmt, gnum, cden);
    ltc_kernel<<<BB, 1024, 0, stream>>>(
        x, input_w, input_b, halt_w, halt_b, output_w, output_b,
        rab, rwp, sab, swp, cmt, gnum, cden,
        readout, h_state, ponder);
}

// Round 3
// 11717.068 us; speedup vs baseline: 2.8130x; 2.8130x over previous
//
#include <hip/hip_runtime.h>
#include <hip/hip_fp16.h>

#define LOG2E 1.44269504088896340736f
#define BB 256
#define TT 128
#define SS 128
#define UU 256

// ---------------- parameter precompute ----------------
// sigmoid(sigma*(v-mu)) = 1/(1+2^(a*v+b)), a=-sigma*log2e, b=sigma*mu*log2e
// wsel = (softplus(w),0) if erev>0 else (0,softplus(w))  ->  num=P-N, den=P+N
// packed per pair: uint2{ half2(a,b), half2(wP,wN) }  (8 bytes)
__global__ __launch_bounds__(256) void prep_kernel(
    const float* __restrict__ sensory_w, const float* __restrict__ sensory_mu,
    const float* __restrict__ sensory_sigma, const float* __restrict__ sensory_erev,
    const float* __restrict__ w, const float* __restrict__ mu,
    const float* __restrict__ sigma, const float* __restrict__ erev,
    const float* __restrict__ gleak, const float* __restrict__ vleak,
    const float* __restrict__ cm,
    uint2* __restrict__ rabw, uint2* __restrict__ sabw,
    float* __restrict__ cmt, float* __restrict__ gnum, float* __restrict__ cden)
{
    int e = blockIdx.x * 256 + threadIdx.x;
    if (e < UU * UU) {
        float sg = sigma[e], m = mu[e];
        float wp = log1pf(expf(w[e]));
        bool pos = erev[e] > 0.0f;
        __half2 ab = __floats2half2_rn(-sg * LOG2E, sg * m * LOG2E);
        __half2 ws = __floats2half2_rn(pos ? wp : 0.0f, pos ? 0.0f : wp);
        uint2 o;
        o.x = *(unsigned int*)&ab;
        o.y = *(unsigned int*)&ws;
        rabw[e] = o;
    }
    if (e < SS * UU) {
        float sg = sensory_sigma[e], m = sensory_mu[e];
        float wp = log1pf(expf(sensory_w[e]));
        bool pos = sensory_erev[e] > 0.0f;
        __half2 ab = __floats2half2_rn(-sg * LOG2E, sg * m * LOG2E);
        __half2 ws = __floats2half2_rn(pos ? wp : 0.0f, pos ? 0.0f : wp);
        uint2 o;
        o.x = *(unsigned int*)&ab;
        o.y = *(unsigned int*)&ws;
        sabw[e] = o;
    }
    if (e < UU) {
        float gl = log1pf(expf(gleak[e]));
        float c = log1pf(expf(cm[e])) * 6.0f;   // ODE_UNFOLDS=6, ts=1
        cmt[e] = c;
        gnum[e] = gl * vleak[e];
        cden[e] = c + gl + 1e-8f;
    }
}

// one sigmoid-weighted accumulation step (f16 path)
#define STEP(ABBITS, WBITS, VK) do {                                        \
    union { unsigned int ui; __half2 h; } cab_, cw_;                        \
    cab_.ui = (ABBITS); cw_.ui = (WBITS);                                   \
    __half z_ = __hfma(__low2half(cab_.h), (VK), __high2half(cab_.h));      \
    __half ex_ = hexp2(z_);                                                 \
    __half s_ = hrcp(__hadd(ex_, __float2half(1.0f)));                      \
    acc2 = __hfma2(cw_.h, __half2half2(s_), acc2);                          \
} while (0)

#define FLUSH() do {                                                        \
    float2 fl_ = __half22float2(acc2);                                      \
    P += fl_.x; N += fl_.y;                                                 \
    acc2 = __half2half2(__float2half(0.0f));                                \
} while (0)

// ---------------- main kernel: 1 block = 1 batch element, 16 waves ----------------
// wave (qi=wv&3, qj=wv>>2): column j = 64*qj + l.
// i-rows per wave: 48 in registers (rows 48qi..48qi+48) + 16 from LDS (rows 192+16qi..+16).
// v is lane-distributed: lane l holds v[u(l)], u = l<48 ? 48qi+l : 192+16qi+(l-48);
// readlane broadcasts exactly the rows this wave needs. 1 barrier per unfold.
__global__ __launch_bounds__(1024, 4) void ltc_kernel(
    const float* __restrict__ x,
    const float* __restrict__ input_w, const float* __restrict__ input_b,
    const float* __restrict__ halt_w, const float* __restrict__ halt_b,
    const float* __restrict__ out_w, const float* __restrict__ out_b,
    const uint2* __restrict__ rabw, const uint2* __restrict__ sabw,
    const float* __restrict__ cmt_g, const float* __restrict__ gnum_g,
    const float* __restrict__ cden_g,
    float* __restrict__ readout, float* __restrict__ h_state, float* __restrict__ ponder_out)
{
    const int b = blockIdx.x, tid = threadIdx.x;
    const int wv = tid >> 6, l = tid & 63;
    const int qi = wv & 3, qj = wv >> 2;
    const int j = (qj << 6) + l;
    const int u = (l < 48) ? (48 * qi + l) : (192 + 16 * qi + (l - 48));

    __shared__ uint2 rlds[64 * UU];          // 128 KB: rows 192..255
    __shared__ float2 part[2][4][UU];        // 16 KB: (P,N) partials, double-buffered
    __shared__ __half xinh[SS];
    __shared__ float red[4];

    // stage LDS-resident rows (once)
    for (int m = 0; m < 16; ++m) {
        int f = m * 1024 + tid;
        rlds[f] = rabw[(192 << 8) + f];
    }

    // register-resident rows (once): 96 VGPRs
    unsigned int rp_ab[48], rp_w[48];
#pragma unroll
    for (int k = 0; k < 48; ++k) {
        uint2 tp = rabw[((48 * qi + k) << 8) + j];
        rp_ab[k] = tp.x; rp_w[k] = tp.y;
    }

    const float cmtu = cmt_g[u], gnu = gnum_g[u], cdu = cden_g[u];
    const float hwu = halt_w[u], owu = out_w[u], obu = out_b[u];
    const float hb = halt_b[0];
    float iw = 0.f, ibv = 0.f;
    if (tid < SS) { iw = input_w[tid]; ibv = input_b[tid]; }

    float v = 0.0f;
    int vhb = 0;                  // f16 bits of v (for readlane broadcast)
    float pond = 0.0f;
    __syncthreads();

    for (int t = 0; t < TT; ++t) {
        // ---- input mapping (f16 for broadcast use) ----
        if (tid < SS)
            xinh[tid] = __float2half(fmaf(x[((size_t)b * TT + t) * SS + tid], iw, ibv));
        __syncthreads();

        // ---- sensory partials: rows [32qi, 32qi+32), streamed from L2, chunk=4 ----
        {
            float P = 0.f, N = 0.f;
            __half2 acc2 = __half2half2(__float2half(0.0f));
#pragma unroll 1
            for (int c = 0; c < 8; ++c) {
                uint2 buf[4];
#pragma unroll
                for (int m = 0; m < 4; ++m)
                    buf[m] = sabw[((32 * qi + 4 * c + m) << 8) + j];
#pragma unroll
                for (int m = 0; m < 4; ++m) {
                    __half xh = xinh[32 * qi + 4 * c + m];
                    STEP(buf[m].x, buf[m].y, xh);
                }
                FLUSH();
            }
            part[0][qi][j] = make_float2(P, N);
        }
        __syncthreads();
        float basen, based;
        {
            float2 s0 = part[0][0][u], s1 = part[0][1][u];
            float2 s2 = part[0][2][u], s3 = part[0][3][u];
            float Ps = s0.x + s1.x + s2.x + s3.x;
            float Ns = s0.y + s1.y + s2.y + s3.y;
            basen = (Ps - Ns) + gnu;
            based = (Ps + Ns) + cdu;
        }

        int pb = 1;
        float accA = 0.0f, halt_sum = 0.0f, rem = 0.0f;
        int nupd = 0;

        // ---- ACT loop (uniform early exit) ----
#pragma unroll 1
        for (int n = 0; n < 10; ++n) {
#pragma unroll 1
            for (int uu = 0; uu < 6; ++uu) {
                float P = 0.f, N = 0.f;
                __half2 acc2 = __half2half2(__float2half(0.0f));
#pragma unroll
                for (int k = 0; k < 48; ++k) {
                    __half vk = __ushort_as_half(
                        (unsigned short)__builtin_amdgcn_readlane(vhb, k));
                    STEP(rp_ab[k], rp_w[k], vk);
                    if ((k & 15) == 15) FLUSH();
                }
#pragma unroll
                for (int k = 0; k < 16; ++k) {
                    uint2 pr = rlds[((16 * qi + k) << 8) + j];
                    __half vk = __ushort_as_half(
                        (unsigned short)__builtin_amdgcn_readlane(vhb, 48 + k));
                    STEP(pr.x, pr.y, vk);
                }
                FLUSH();
                part[pb][qi][j] = make_float2(P, N);
                __syncthreads();
                // redundant per-wave v-update for own units
                float2 p0 = part[pb][0][u], p1 = part[pb][1][u];
                float2 p2 = part[pb][2][u], p3 = part[pb][3][u];
                float Pt = p0.x + p1.x + p2.x + p3.x;
                float Nt = p0.y + p1.y + p2.y + p3.y;
                float num = (Pt - Nt) + basen;
                float den = (Pt + Nt) + based;
                v = fmaf(cmtu, v, num) * __builtin_amdgcn_rcpf(den);
                vhb = (int)__half_as_ushort(__float2half(v));
                pb ^= 1;
            }

            // halting p = sigmoid(v . halt_w + hb); qj==0 waves hold all 256 units
            if (qj == 0) {
                float hp = v * hwu;
                hp += __shfl_down(hp, 32, 64);
                hp += __shfl_down(hp, 16, 64);
                hp += __shfl_down(hp, 8, 64);
                hp += __shfl_down(hp, 4, 64);
                hp += __shfl_down(hp, 2, 64);
                hp += __shfl_down(hp, 1, 64);
                if (l == 0) red[qi] = hp;
            }
            __syncthreads();
            float dot = red[0] + red[1] + red[2] + red[3] + hb;
            float pr = __builtin_amdgcn_rcpf(1.0f + __builtin_amdgcn_exp2f(-dot * LOG2E));
            float new_sum = halt_sum + pr;
            bool halting = (n == 9) || (new_sum >= 0.99f);
            float r = 1.0f - halt_sum;
            float wgt = halting ? r : pr;
            accA = fmaf(wgt, v, accA);
            if (halting) rem += r;
            halt_sum = new_sum;
            ++nupd;
            if (halting) break;
        }

        // ---- t epilogue: new_state = accA ----
        if (qj == 0)
            readout[((size_t)b * TT + t) * UU + u] = fmaf(accA, owu, obu);
        v = accA;
        vhb = (int)__half_as_ushort(__float2half(v));
        pond += (float)nupd + rem;
    }

    if (qj == 0) h_state[(size_t)b * UU + u] = v;
    if (tid == 0) atomicAdd(ponder_out, pond * (1.0f / BB));
}

// ---------------- launch ----------------
extern "C" void kernel_launch(void* const* d_in, const int* in_sizes, int n_in,
                              void* d_out, int out_size, void* d_ws, size_t ws_size,
                              hipStream_t stream)
{
    const float* x             = (const float*)d_in[0];
    const float* input_w       = (const float*)d_in[1];
    const float* input_b       = (const float*)d_in[2];
    const float* sensory_w     = (const float*)d_in[3];
    const float* sensory_mu    = (const float*)d_in[4];
    const float* sensory_sigma = (const float*)d_in[5];
    const float* sensory_erev  = (const float*)d_in[6];
    const float* w             = (const float*)d_in[7];
    const float* mu            = (const float*)d_in[8];
    const float* sigma         = (const float*)d_in[9];
    const float* erev          = (const float*)d_in[10];
    const float* gleak         = (const float*)d_in[11];
    const float* vleak         = (const float*)d_in[12];
    const float* cm            = (const float*)d_in[13];
    const float* output_w      = (const float*)d_in[14];
    const float* output_b      = (const float*)d_in[15];
    const float* halt_w        = (const float*)d_in[16];
    const float* halt_b        = (const float*)d_in[17];

    float* readout = (float*)d_out;
    float* h_state = readout + (size_t)BB * TT * UU;
    float* ponder  = h_state + (size_t)BB * UU;

    char* wsb = (char*)d_ws;
    uint2* rabw = (uint2*)wsb;  wsb += (size_t)UU * UU * sizeof(uint2);
    uint2* sabw = (uint2*)wsb;  wsb += (size_t)SS * UU * sizeof(uint2);
    float* cmt  = (float*)wsb;  wsb += (size_t)UU * 4;
    float* gnum = (float*)wsb;  wsb += (size_t)UU * 4;
    float* cden = (float*)wsb;  wsb += (size_t)UU * 4;

    hipMemsetAsync(ponder, 0, sizeof(float), stream);
    prep_kernel<<<(UU * UU) / 256, 256, 0, stream>>>(
        sensory_w, sensory_mu, sensory_sigma, sensory_erev,
        w, mu, sigma, erev, gleak, vleak, cm,
        rabw, sabw, cmt, gnum, cden);
    ltc_kernel<<<BB, 1024, 0, stream>>>(
        x, input_w, input_b, halt_w, halt_b, output_w, output_b,
        rabw, sabw, cmt, gnum, cden,
        readout, h_state, ponder);
}